// Round 2
// baseline (545.067 us; speedup 1.0000x reference)
//
#include <hip/hip_runtime.h>

// WeightController: PI-style integral update + history-buffer shift.
//
// Outputs (concatenated flat in d_out, fp32):
//   [0 : 2048)                       weight_state_next
//   [2048 : 2048 + 8000*2048*5)      recording_next (history, batch, vars)
//
// recording_next[t]   = recording[t+1]        for t in [0, 7999)
// recording_next[7999, i, :] = (cv, ws_next, to_int, rl, e)
//
// Roofline: 327.6 MB read + 327.7 MB write = ~655 MB -> ~104 us at the
// 6.29 TB/s measured copy ceiling. Timed dur_us additionally contains
// ~410 us of harness re-poison fills (1.31 GB fillBufferAligned x2) that
// kernel source cannot influence.
//
// R1 post-mortem: hipMemcpyAsync was a ~5.75 TB/s blit (not SDMA);
// naive grid-stride float4 kernel was slightly slower (~5.2 TB/s).
// R2: 4-way unrolled loads (MLP) + non-temporal hints (stream is 2.5x L3,
// touched once -- don't thrash caches).

#define N_BATCH     2048
#define N_HISTORY   8000
#define N_VARS      5
#define REF_V       (-0.2f)
#define K_I_V       (4.0f)
#define RATE_MAX_V  (0.01f)
#define RATE_MIN_V  (-0.02f)
#define LAMBDA_V    (1.5f)

// 7999 * 2048 * 5 floats = 81,909,760 floats = 20,477,440 float4 (exact).
#define COPY_VEC4   20477440u
#define GRID_BLKS   2048
#define BLK_THREADS 256

// Native vector type: __builtin_nontemporal_* requires scalar/vector,
// not HIP's float4 class.
typedef float f4 __attribute__((ext_vector_type(4)));

__global__ __launch_bounds__(BLK_THREADS) void wc_fused_kernel(
    const float* __restrict__ cv,
    const float* __restrict__ ws,
    const float* __restrict__ rec_in,
    float* __restrict__ out) {
    const unsigned tid    = blockIdx.x * blockDim.x + threadIdx.x;
    const unsigned stride = GRID_BLKS * BLK_THREADS;   // 524,288 threads

    // ---- Bulk shift: recording[1:] -> recording_next[:7999] ----
    // src offset 40960 B, dst offset 8192 B: both 16B-aligned, float4 exact.
    const f4* __restrict__ src =
        reinterpret_cast<const f4*>(rec_in + (size_t)N_BATCH * N_VARS);
    f4* __restrict__ dst =
        reinterpret_cast<f4*>(out + N_BATCH);

    // 4-way unrolled: 4 independent loads in flight before stores.
    unsigned v = tid;
    const unsigned limit4 = COPY_VEC4 - 3u * stride;  // 20,477,440 > 3*stride
    while (v < limit4) {
        f4 a = __builtin_nontemporal_load(&src[v]);
        f4 b = __builtin_nontemporal_load(&src[v +      stride]);
        f4 c = __builtin_nontemporal_load(&src[v + 2u * stride]);
        f4 d = __builtin_nontemporal_load(&src[v + 3u * stride]);
        __builtin_nontemporal_store(a, &dst[v]);
        __builtin_nontemporal_store(b, &dst[v +      stride]);
        __builtin_nontemporal_store(c, &dst[v + 2u * stride]);
        __builtin_nontemporal_store(d, &dst[v + 3u * stride]);
        v += 4u * stride;
    }
    for (; v < COPY_VEC4; v += stride) {
        __builtin_nontemporal_store(__builtin_nontemporal_load(&src[v]),
                                    &dst[v]);
    }

    // ---- Controller update + last record row (first 2048 threads) ----
    if (tid < N_BATCH) {
        const int i  = (int)tid;
        float c2     = cv[i];
        float e      = REF_V - c2;
        float to_int = K_I_V * e;
        float rl     = fminf(fmaxf(to_int, RATE_MIN_V), RATE_MAX_V);
        float wn     = fminf(fmaxf(ws[i] + rl, 0.0f), LAMBDA_V);

        out[i] = wn;  // weight_state_next

        float* rec = out + N_BATCH
                   + (size_t)(N_HISTORY - 1) * N_BATCH * N_VARS
                   + (size_t)i * N_VARS;
        rec[0] = c2;
        rec[1] = wn;
        rec[2] = to_int;
        rec[3] = rl;
        rec[4] = e;
    }
}

extern "C" void kernel_launch(void* const* d_in, const int* in_sizes, int n_in,
                              void* d_out, int out_size, void* d_ws, size_t ws_size,
                              hipStream_t stream) {
    const float* cv  = (const float*)d_in[0];   // controlled_variable (2048,)
    const float* ws  = (const float*)d_in[1];   // weight_state (2048,)
    const float* rec = (const float*)d_in[2];   // recording (8000, 2048, 5)
    float* out = (float*)d_out;

    wc_fused_kernel<<<GRID_BLKS, BLK_THREADS, 0, stream>>>(cv, ws, rec, out);
}

// Round 3
// 525.296 us; speedup vs baseline: 1.0376x; 1.0376x over previous
//
#include <hip/hip_runtime.h>

// WeightController: PI-style integral update + history-buffer shift.
//
// Outputs (concatenated flat in d_out, fp32):
//   [0 : 2048)                       weight_state_next
//   [2048 : 2048 + 8000*2048*5)      recording_next (history, batch, vars)
//
// recording_next[t]   = recording[t+1]        for t in [0, 7999)
// recording_next[7999, i, :] = (cv, ws_next, to_int, rl, e)
//
// Roofline accounting (3 rounds of evidence):
//   - Harness-fixed: 2x 1.31 GB fillBufferAligned re-poisons ~= 410 us
//     (present in every round's rocprof, untouchable from kernel source).
//   - Controllable: 327.6 MB read + 327.7 MB write = 655 MB.
//     Ideal @6.29 TB/s copy ceiling = 104 us.
//   - Measured copy paths: runtime blit 114 us (5.75 TB/s)  <- BEST
//                          naive grid-stride float4 kernel 125 us
//                          +nontemporal +4-way unroll       135 us
// R3: revert to the runtime blit (R0 structure). Custom copy kernels
// regressed twice; the blit is within ~10 us (noise band) of the ceiling.

#define N_BATCH     2048
#define N_HISTORY   8000
#define N_VARS      5
#define REF_V       (-0.2f)
#define K_I_V       (4.0f)
#define RATE_MAX_V  (0.01f)
#define RATE_MIN_V  (-0.02f)
#define LAMBDA_V    (1.5f)

__global__ __launch_bounds__(256) void wc_update_kernel(
    const float* __restrict__ cv,
    const float* __restrict__ ws,
    float* __restrict__ out) {
    int i = blockIdx.x * blockDim.x + threadIdx.x;
    if (i >= N_BATCH) return;

    float c      = cv[i];
    float e      = REF_V - c;
    float to_int = K_I_V * e;
    float rl     = fminf(fmaxf(to_int, RATE_MIN_V), RATE_MAX_V);
    float wn     = fminf(fmaxf(ws[i] + rl, 0.0f), LAMBDA_V);

    // Output 0: weight_state_next
    out[i] = wn;

    // Last history row of recording_next: (cv, ws_next, to_int, rl, e)
    float* rec = out + N_BATCH
               + (size_t)(N_HISTORY - 1) * N_BATCH * N_VARS
               + (size_t)i * N_VARS;
    rec[0] = c;
    rec[1] = wn;
    rec[2] = to_int;
    rec[3] = rl;
    rec[4] = e;
}

extern "C" void kernel_launch(void* const* d_in, const int* in_sizes, int n_in,
                              void* d_out, int out_size, void* d_ws, size_t ws_size,
                              hipStream_t stream) {
    const float* cv  = (const float*)d_in[0];   // controlled_variable (2048,)
    const float* ws  = (const float*)d_in[1];   // weight_state (2048,)
    const float* rec = (const float*)d_in[2];   // recording (8000, 2048, 5)
    float* out = (float*)d_out;

    // Bulk shift: recording[1:] -> recording_next[:7999]
    // Runtime D2D blit measured at 5.75 TB/s -- fastest of three copy
    // implementations tried (see header).
    const size_t row_elems  = (size_t)N_BATCH * N_VARS;             // 10240
    const size_t copy_elems = (size_t)(N_HISTORY - 1) * row_elems;  // 81,909,760
    hipMemcpyAsync(out + N_BATCH,            // dst: recording_next row 0
                   rec + row_elems,          // src: recording row 1
                   copy_elems * sizeof(float),
                   hipMemcpyDeviceToDevice, stream);

    // Controller update + last record row (tiny, 8 waves)
    wc_update_kernel<<<(N_BATCH + 255) / 256, 256, 0, stream>>>(cv, ws, out);
}